// Round 2
// baseline (973.059 us; speedup 1.0000x reference)
//
#include <hip/hip_runtime.h>

typedef unsigned int uint;

#define DEV __device__ __forceinline__

// If p1/p2/s2 outputs mismatch while action matches, flip to 0 (old JAX
// non-partitionable threefry semantics).
#define JAX_PARTITIONABLE 1

// ---------- problem constants ----------
constexpr int NN  = 100000;   // nodes
constexpr int G   = 256;      // colsum partial blocks
constexpr int RPB = 391;      // rows per colsum block (G*RPB = 100096 >= NN)

// ws layout (float offsets)
constexpr int XCAT  = 0;      // 2560: [h_embed | h_hist | goal_obj | goal_embed | pred_hist]
constexpr int GOWS  = 2560;   // 4096: go (8 x 512)
constexpr int WHH0  = 6656;   // 2048: lstm_Whh@h0 + bih + bhh
constexpr int FINALW= 8704;   // 512
constexpr int PART  = 9216;   // G*512 colsum partials

// out offsets (elements)
constexpr int O_ACT=0, O_P1=11, O_P2=139, O_S2=267, O_ACTI=283, O_P1I=294,
              O_P2I=422, O_S2I=550, O_HH=566, O_C1=1078, O_PH=1590, O_CP1=2102;

struct Args {
  const float *h, *goalVec, *gObj, *pe, *pie, *h0, *c0, *hp0, *cp0, *prelu;
  const float *W_sbert,*b_sbert,*W_cn,*b_cn,*W_gembed,*b_gembed,*W_goattn,*b_goattn,*W_fc,*b_fc;
  const float *lWih,*lWhh,*lbih,*lbhh,*pWih,*pWhh,*pbih,*pbhh;
  const float *W_act,*b_act,*W_obj1,*b_obj1,*W_obj2,*b_obj2,*W_state,*b_state;
  const float *W_acti,*b_acti,*W_obj1i,*b_obj1i;
  float* out;
  float* ws;
};

// ---------- small utils ----------
DEV float sigm(float x){ return 1.f/(1.f+expf(-x)); }
DEV float preluf(float x, float a){ return x >= 0.f ? x : a*x; }

DEV float wred(float v){
  #pragma unroll
  for (int off=32; off; off>>=1) v += __shfl_xor(v, off, 64);
  return v;
}

// one wave computes one dot; result broadcast to all lanes.
DEV float wdotf4(const float* w, const float* x, int n4, int lane){ // both 16B-aligned
  float acc = 0.f;
  for (int c = lane; c < n4; c += 64){
    float4 a = ((const float4*)w)[c];
    float4 b = ((const float4*)x)[c];
    acc += a.x*b.x + a.y*b.y + a.z*b.z + a.w*b.w;
  }
  return wred(acc);
}
DEV float wdotf2(const float* w, const float* x, int n2, int lane){ // 8B-aligned w
  float acc = 0.f;
  for (int c = lane; c < n2; c += 64){
    float2 a = ((const float2*)w)[c];
    acc += a.x*x[2*c] + a.y*x[2*c+1];
  }
  return wred(acc);
}

// full-wave softmax over values at idx=lane (v0) and idx=64+lane (v1); -INF = absent
DEV void wsoftmax2(float v0, float v1, float& p0, float& p1){
  float m = fmaxf(v0, v1);
  #pragma unroll
  for (int off=32; off; off>>=1) m = fmaxf(m, __shfl_xor(m, off, 64));
  float e0 = (v0 == -INFINITY) ? 0.f : expf(v0 - m);
  float e1 = (v1 == -INFINITY) ? 0.f : expf(v1 - m);
  float s = e0 + e1;
  #pragma unroll
  for (int off=32; off; off>>=1) s += __shfl_xor(s, off, 64);
  float inv = 1.f / s;
  p0 = e0 * inv; p1 = e1 * inv;
}

// ---------- JAX threefry2x32 (20 rounds) ----------
DEV void threefry(uint k0, uint k1, uint x0, uint x1, uint& o0, uint& o1){
  uint ks2 = k0 ^ k1 ^ 0x1BD11BDAu;
  x0 += k0; x1 += k1;
  #define TFR(r) { x0 += x1; x1 = (x1<<(r))|(x1>>(32-(r))); x1 ^= x0; }
  TFR(13) TFR(15) TFR(26) TFR(6)   x0 += k1;  x1 += ks2 + 1u;
  TFR(17) TFR(29) TFR(16) TFR(24)  x0 += ks2; x1 += k0 + 2u;
  TFR(13) TFR(15) TFR(26) TFR(6)   x0 += k0;  x1 += k1 + 3u;
  TFR(17) TFR(29) TFR(16) TFR(24)  x0 += k1;  x1 += ks2 + 4u;
  TFR(13) TFR(15) TFR(26) TFR(6)   x0 += ks2; x1 += k0 + 5u;
  #undef TFR
  o0 = x0; o1 = x1;
}

// subkey i of jax.random.split(jax.random.key(42), 4)
DEV void jax_subkey(int i, uint& k0, uint& k1){
#if JAX_PARTITIONABLE
  threefry(0u, 42u, 0u, (uint)i, k0, k1);       // fold-like split
#else
  uint L[4], H[4];
  #pragma unroll
  for (int p=0;p<4;p++) threefry(0u,42u,(uint)p,(uint)(4+p),L[p],H[p]);
  uint kk[4][2] = {{L[0],L[1]},{L[2],L[3]},{H[0],H[1]},{H[2],H[3]}};
  k0 = kk[i][0]; k1 = kk[i][1];
#endif
}

DEV uint jax_bits(uint k0, uint k1, int idx, int n){
#if JAX_PARTITIONABLE
  uint o0,o1; threefry(k0,k1,0u,(uint)idx,o0,o1);
  return o0 ^ o1;
#else
  int m = (n+1)/2;
  int p = (idx < m) ? idx : idx - m;
  uint c1 = (p + m <= n-1) ? (uint)(p + m) : 0u;
  uint o0,o1; threefry(k0,k1,(uint)p,c1,o0,o1);
  return (idx < m) ? o0 : o1;
#endif
}

DEV float jax_gumbel(uint k0, uint k1, int idx, int n){
  uint bits = jax_bits(k0,k1,idx,n);
  float f = __uint_as_float((bits >> 9) | 0x3f800000u) - 1.0f;   // [0,1)
  float u = fmaxf(1e-10f, f + 1e-10f);                           // uniform(1e-10, 1.0)
  return -logf(-logf(u));
}

// ================= K1: colsum partials + independent gemvs =================
__global__ __launch_bounds__(256) void k1(Args A){
  __shared__ float sm[2048];
  const int t = threadIdx.x, b = blockIdx.x;
  const int wv = t >> 6, lane = t & 63;
  const float pa = A.prelu[0];

  if (b < G){                                   // ---- h column-sum partials
    const int cg = t & 127, rl = t >> 7;        // 128 col-groups x 4 floats, 2 row-lanes
    long r0 = (long)b * RPB;
    long r1 = r0 + RPB; if (r1 > NN) r1 = NN;
    float ax=0.f, ay=0.f, az=0.f, aw=0.f;
    for (long r = r0 + rl; r < r1; r += 2){
      float4 v = *(const float4*)(A.h + (size_t)r*512 + cg*4);
      ax += v.x; ay += v.y; az += v.z; aw += v.w;
    }
    sm[rl*512 + cg*4 + 0] = ax;
    sm[rl*512 + cg*4 + 1] = ay;
    sm[rl*512 + cg*4 + 2] = az;
    sm[rl*512 + cg*4 + 3] = aw;
    __syncthreads();
    for (int c = t; c < 512; c += 256)
      A.ws[PART + b*512 + c] = sm[c] + sm[512+c];
  } else if (b < G + 128){                      // ---- goal_embed = prelu(W_sbert@goalVec + b)
    int row = (b - G)*4 + wv;
    float d = wdotf4(A.W_sbert + row*384, A.goalVec, 96, lane) + A.b_sbert[row];
    if (lane==0) A.ws[XCAT + 1536 + row] = preluf(d, pa);
  } else if (b < G + 128 + 1024){               // ---- go[g][j] = prelu(W_cn@gObj[g] + b)
    int idx = (b - G - 128)*4 + wv;
    int g = idx >> 9, j = idx & 511;
    float d = wdotf4(A.W_cn + j*300, A.gObj + g*300, 75, lane) + A.b_cn[j];
    if (lane==0) A.ws[GOWS + idx] = preluf(d, pa);
  } else if (b < G + 128 + 1024 + 128){         // ---- predicate LSTM cell
    float* xp = sm;          // 1222
    float* hp = sm + 1222;   // 512
    for (int i=t;i<611;i+=256) xp[i]       = A.pe[i];
    for (int i=t;i<611;i+=256) xp[611+i]   = A.pie[i];
    for (int i=t;i<512;i+=256) hp[i]       = A.hp0[i];
    __syncthreads();
    int j = (b - (G+128+1024))*4 + wv;
    float z[4];
    #pragma unroll
    for (int q=0;q<4;q++){
      int row = j + q*512;
      float d = wdotf2(A.pWih + (size_t)row*1222, xp, 611, lane);
      d += wdotf4(A.pWhh + (size_t)row*512, hp, 128, lane);
      z[q] = d + A.pbih[row] + A.pbhh[row];
    }
    if (lane==0){
      float cc = sigm(z[1])*A.cp0[j] + sigm(z[0])*tanhf(z[2]);
      float hh = sigm(z[3])*tanhf(cc);
      A.ws[XCAT + 2048 + j] = hh;
      A.out[O_PH + j]  = hh;
      A.out[O_CP1 + j] = cc;
    }
  } else {                                      // ---- whh0[k] = lWhh[k]@h0 + bih + bhh
    int k = (b - (G+128+1024+128))*4 + wv;
    float d = wdotf4(A.lWhh + (size_t)k*512, A.h0, 128, lane)
            + A.lbih[k] + A.lbhh[k];
    if (lane==0) A.ws[WHH0 + k] = d;
  }
}

// ================= K2: reduce partials + W_gembed gemv -> h_embed ==========
__global__ __launch_bounds__(256) void k2(Args A){
  __shared__ float red[2][512];
  __shared__ float xcs[512];
  const int t = threadIdx.x;
  const int chunk = t & 127, half = t >> 7;
  float4 a = make_float4(0.f,0.f,0.f,0.f);
  const float4* p4 = (const float4*)(A.ws + PART);
  for (int g = half*128; g < half*128 + 128; ++g){
    float4 v = p4[g*128 + chunk];
    a.x += v.x; a.y += v.y; a.z += v.z; a.w += v.w;
  }
  *(float4*)&red[half][chunk*4] = a;
  __syncthreads();
  if (t < 128){
    float4 u = *(float4*)&red[0][t*4];
    float4 v = *(float4*)&red[1][t*4];
    float4 s = make_float4(u.x+v.x, u.y+v.y, u.z+v.z, u.w+v.w);
    *(float4*)&xcs[t*4] = s;
  }
  __syncthreads();
  const int wv = t >> 6, lane = t & 63;
  const float pa = A.prelu[0];
  #pragma unroll
  for (int r = 0; r < 2; ++r){
    int row = blockIdx.x*8 + wv + r*4;
    float d = wdotf4(A.W_gembed + (size_t)row*512, xcs, 128, lane) + A.b_gembed[row];
    if (lane==0) A.ws[XCAT + row] = preluf(d, pa);
  }
}

// ================= K3: graph LSTM + goal-object attention ==================
__global__ __launch_bounds__(256) void k3(Args A){
  __shared__ float sm[4624];   // [0,512): h_embed; [512,4608): go; [4608,4616): tl; [4616,4624): aw
  const int t = threadIdx.x, b = blockIdx.x;
  const int wv = t >> 6, lane = t & 63;
  float* sh = sm;
  for (int i=t;i<512;i+=256) sh[i] = A.ws[XCAT + i];
  if (b < 128){
    __syncthreads();
    int j = b*4 + wv;
    float zi = wdotf4(A.lWih + (size_t)(j       )*512, sh, 128, lane) + A.ws[WHH0 + j];
    float zf = wdotf4(A.lWih + (size_t)(j +  512)*512, sh, 128, lane) + A.ws[WHH0 + j + 512];
    float zg = wdotf4(A.lWih + (size_t)(j + 1024)*512, sh, 128, lane) + A.ws[WHH0 + j + 1024];
    float zo = wdotf4(A.lWih + (size_t)(j + 1536)*512, sh, 128, lane) + A.ws[WHH0 + j + 1536];
    if (lane==0){
      float cc = sigm(zf)*A.c0[j] + sigm(zi)*tanhf(zg);
      float hh = sigm(zo)*tanhf(cc);
      A.ws[XCAT + 512 + j] = hh;
      A.out[O_HH + j] = hh;
      A.out[O_C1 + j] = cc;
    }
  } else {
    float* sgo = sm + 512; float* tl = sm + 4608; float* aw = sm + 4616;
    for (int i=t;i<4096;i+=256) sgo[i] = A.ws[GOWS + i];
    __syncthreads();
    float common = wdotf4(A.W_goattn, sh, 128, lane);
    for (int g = wv; g < 8; g += 4){
      float t2 = wdotf4(A.W_goattn + 512, sgo + g*512, 128, lane);
      if (lane==0) tl[g] = common + t2 + A.b_goattn[0];
    }
    __syncthreads();
    if (wv == 0){
      float v0 = lane < 8 ? tl[lane] : -INFINITY;
      float p0, p1; wsoftmax2(v0, -INFINITY, p0, p1);
      if (lane < 8) aw[lane] = p0;
    }
    __syncthreads();
    for (int j = t; j < 512; j += 256){
      float s = 0.f;
      #pragma unroll
      for (int g=0; g<8; g++) s += aw[g]*sgo[g*512 + j];
      A.ws[XCAT + 1024 + j] = s;
    }
  }
}

// ================= K4: final = prelu(W_fc @ xcat + b_fc) ===================
__global__ __launch_bounds__(256) void k4(Args A){
  __shared__ float xc[2560];
  const int t = threadIdx.x;
  for (int i=t;i<2560;i+=256) xc[i] = A.ws[XCAT + i];
  __syncthreads();
  const int wv = t >> 6, lane = t & 63;
  const float pa = A.prelu[0];
  int row = blockIdx.x*4 + wv;
  float d = wdotf4(A.W_fc + (size_t)row*2560, xc, 640, lane) + A.b_fc[row];
  if (lane==0) A.ws[FINALW + row] = preluf(d, pa);
}

// ================= K5: both decode chains (single block) ===================
__global__ __launch_bounds__(256) void k5(Args A){
  __shared__ float sf[512];
  __shared__ float xf[651], xi[651];
  __shared__ float la[2][11];
  __shared__ float lg[2][128];
  __shared__ float ls[2][16];
  __shared__ uint kk[4][2];
  const int t = threadIdx.x, wv = t >> 6, lane = t & 63;
  for (int i=t;i<512;i+=256){ float v = A.ws[FINALW + i]; sf[i]=v; xf[i]=v; xi[i]=v; }
  if (t < 4){ uint a,b2; jax_subkey(t, a, b2); kk[t][0]=a; kk[t][1]=b2; }
  __syncthreads();
  // action / action_inv logits (22 rows of len-512)
  for (int r = wv; r < 22; r += 4){
    int chain = r >= 11; int rr = chain ? r - 11 : r;
    const float* W  = chain ? A.W_acti : A.W_act;
    const float* bb = chain ? A.b_acti : A.b_act;
    float d = wdotf4(W + (size_t)rr*512, sf, 128, lane) + bb[rr];
    if (lane==0) la[chain][rr] = d;
  }
  __syncthreads();
  if (wv < 2){
    int chain = wv;
    float v0 = lane < 11 ? la[chain][lane] : -INFINITY;
    float p0, pd; wsoftmax2(v0, -INFINITY, p0, pd);
    if (lane < 11) A.out[(chain ? O_ACTI : O_ACT) + lane] = p0;
    uint k0 = kk[chain ? 2 : 0][0], k1 = kk[chain ? 2 : 0][1];
    float gl = lane < 11 ? (p0 + jax_gumbel(k0,k1,lane,11)) / 0.01f : -INFINITY;
    float o0, o1; wsoftmax2(gl, -INFINITY, o0, o1);
    if (lane < 11) (chain ? xi : xf)[512 + lane] = o0;
  }
  __syncthreads();
  // p1 / p1_inv logits (256 rows of len-523; odd stride -> scalar loads)
  for (int r = wv; r < 256; r += 4){
    int chain = r >= 128; int rr = r & 127;
    const float* W  = chain ? A.W_obj1i : A.W_obj1;
    const float* bb = chain ? A.b_obj1i : A.b_obj1;
    const float* x = chain ? xi : xf;
    const float* wr = W + (size_t)rr*523;
    float acc = 0.f;
    for (int i = lane; i < 523; i += 64) acc += wr[i] * x[i];
    acc = wred(acc) + bb[rr];
    if (lane==0) lg[chain][rr] = acc;
  }
  __syncthreads();
  if (wv < 2){
    int chain = wv;
    float p0, p1; wsoftmax2(lg[chain][lane], lg[chain][64+lane], p0, p1);
    int base = chain ? O_P1I : O_P1;
    A.out[base + lane] = p0; A.out[base + 64 + lane] = p1;
    uint k0 = kk[chain ? 3 : 1][0], k1 = kk[chain ? 3 : 1][1];
    float g0 = (p0 + jax_gumbel(k0,k1,lane,128))    / 0.01f;
    float g1 = (p1 + jax_gumbel(k0,k1,lane+64,128)) / 0.01f;
    float o0, o1; wsoftmax2(g0, g1, o0, o1);
    float* x = chain ? xi : xf;
    x[523 + lane] = o0; x[523 + 64 + lane] = o1;
  }
  __syncthreads();
  // p2/s2 (shared weights for fwd + inv): 288 rows of len-651
  for (int r = wv; r < 288; r += 4){
    int chain = r >= 144; int q = chain ? r - 144 : r;
    bool st = q >= 128; int rr = st ? q - 128 : q;
    const float* W  = st ? A.W_state : A.W_obj2;
    const float* bb = st ? A.b_state : A.b_obj2;
    const float* x = chain ? xi : xf;
    const float* wr = W + (size_t)rr*651;
    float acc = 0.f;
    for (int i = lane; i < 651; i += 64) acc += wr[i] * x[i];
    acc = wred(acc) + bb[rr];
    if (lane==0){ if (st) ls[chain][rr] = acc; else lg[chain][rr] = acc; }
  }
  __syncthreads();
  if (wv < 2){
    int chain = wv;
    float p0, p1; wsoftmax2(lg[chain][lane], lg[chain][64+lane], p0, p1);
    int base = chain ? O_P2I : O_P2;
    A.out[base + lane] = p0; A.out[base + 64 + lane] = p1;
  } else {
    int chain = wv - 2;
    float v0 = lane < 16 ? ls[chain][lane] : -INFINITY;
    float p0, p1; wsoftmax2(v0, -INFINITY, p0, p1);
    int base = chain ? O_S2I : O_S2;
    if (lane < 16) A.out[base + lane] = p0;
  }
}

// ================= host =================
extern "C" void kernel_launch(void* const* d_in, const int* in_sizes, int n_in,
                              void* d_out, int out_size, void* d_ws, size_t ws_size,
                              hipStream_t stream){
  Args A;
  A.h       = (const float*)d_in[0];
  A.goalVec = (const float*)d_in[1];
  A.gObj    = (const float*)d_in[2];
  A.pe      = (const float*)d_in[3];
  A.pie     = (const float*)d_in[4];
  A.h0      = (const float*)d_in[5];
  A.c0      = (const float*)d_in[6];
  A.hp0     = (const float*)d_in[7];
  A.cp0     = (const float*)d_in[8];
  A.prelu   = (const float*)d_in[9];
  A.W_sbert = (const float*)d_in[10]; A.b_sbert = (const float*)d_in[11];
  A.W_cn    = (const float*)d_in[12]; A.b_cn    = (const float*)d_in[13];
  // d_in[14], d_in[15] (W_gattn, b_gattn) are mathematically dead: softmax over axis of size 1 == 1.0
  A.W_gembed= (const float*)d_in[16]; A.b_gembed= (const float*)d_in[17];
  A.W_goattn= (const float*)d_in[18]; A.b_goattn= (const float*)d_in[19];
  A.W_fc    = (const float*)d_in[20]; A.b_fc    = (const float*)d_in[21];
  A.lWih    = (const float*)d_in[22]; A.lWhh    = (const float*)d_in[23];
  A.lbih    = (const float*)d_in[24]; A.lbhh    = (const float*)d_in[25];
  A.pWih    = (const float*)d_in[26]; A.pWhh    = (const float*)d_in[27];
  A.pbih    = (const float*)d_in[28]; A.pbhh    = (const float*)d_in[29];
  A.W_act   = (const float*)d_in[30]; A.b_act   = (const float*)d_in[31];
  A.W_obj1  = (const float*)d_in[32]; A.b_obj1  = (const float*)d_in[33];
  A.W_obj2  = (const float*)d_in[34]; A.b_obj2  = (const float*)d_in[35];
  A.W_state = (const float*)d_in[36]; A.b_state = (const float*)d_in[37];
  A.W_acti  = (const float*)d_in[38]; A.b_acti  = (const float*)d_in[39];
  A.W_obj1i = (const float*)d_in[40]; A.b_obj1i = (const float*)d_in[41];
  A.out = (float*)d_out;
  A.ws  = (float*)d_ws;

  k1<<<G + 128 + 1024 + 128 + 512, 256, 0, stream>>>(A);  // 2048 blocks
  k2<<<64,  256, 0, stream>>>(A);
  k3<<<129, 256, 0, stream>>>(A);
  k4<<<128, 256, 0, stream>>>(A);
  k5<<<1,   256, 0, stream>>>(A);
}

// Round 3
// 474.786 us; speedup vs baseline: 2.0495x; 2.0495x over previous
//
#include <hip/hip_runtime.h>

typedef unsigned int uint;

#define DEV __device__ __forceinline__

#define JAX_PARTITIONABLE 1   // confirmed correct by round-2 pass

// ---------- problem constants ----------
constexpr int NN  = 100000;   // nodes
constexpr int G   = 256;      // colsum partial blocks
constexpr int RPB = 391;      // rows per colsum block (G*RPB = 100096 >= NN)

// ws layout (float offsets)
constexpr int XCAT  = 0;      // 2560: [h_embed | h_hist | goal_obj | goal_embed | pred_hist]
constexpr int GOWS  = 2560;   // 4096: go (8 x 512)
constexpr int WHH0  = 6656;   // 2048: lstm_Whh@h0 + bih + bhh
constexpr int FINALW= 8704;   // 512
constexpr int B1F   = 9216;   // 256: obj1 base (fwd 128, inv 128)
constexpr int B2F   = 9472;   // 128: obj2 base (shared by fwd/inv)
constexpr int BSF   = 9600;   // 16:  state base (shared)
constexpr int LAW   = 9616;   // 22:  action logits (fwd 11, inv 11)
constexpr int PART  = 9728;   // G*512 colsum partials

// out offsets (elements)
constexpr int O_ACT=0, O_P1=11, O_P2=139, O_S2=267, O_ACTI=283, O_P1I=294,
              O_P2I=422, O_S2I=550, O_HH=566, O_C1=1078, O_PH=1590, O_CP1=2102;

struct Args {
  const float *h, *goalVec, *gObj, *pe, *pie, *h0, *c0, *hp0, *cp0, *prelu;
  const float *W_sbert,*b_sbert,*W_cn,*b_cn,*W_gembed,*b_gembed,*W_goattn,*b_goattn,*W_fc,*b_fc;
  const float *lWih,*lWhh,*lbih,*lbhh,*pWih,*pWhh,*pbih,*pbhh;
  const float *W_act,*b_act,*W_obj1,*b_obj1,*W_obj2,*b_obj2,*W_state,*b_state;
  const float *W_acti,*b_acti,*W_obj1i,*b_obj1i;
  float* out;
  float* ws;
};

// ---------- small utils ----------
DEV float sigm(float x){ return 1.f/(1.f+expf(-x)); }
DEV float preluf(float x, float a){ return x >= 0.f ? x : a*x; }

DEV float wred(float v){
  #pragma unroll
  for (int off=32; off; off>>=1) v += __shfl_xor(v, off, 64);
  return v;
}

DEV float wdotf4(const float* w, const float* x, int n4, int lane){ // both 16B-aligned
  float acc = 0.f;
  for (int c = lane; c < n4; c += 64){
    float4 a = ((const float4*)w)[c];
    float4 b = ((const float4*)x)[c];
    acc += a.x*b.x + a.y*b.y + a.z*b.z + a.w*b.w;
  }
  return wred(acc);
}
DEV float wdotf2(const float* w, const float* x, int n2, int lane){ // 8B-aligned w
  float acc = 0.f;
  #pragma unroll 4
  for (int c = lane; c < n2; c += 64){
    float2 a = ((const float2*)w)[c];
    acc += a.x*x[2*c] + a.y*x[2*c+1];
  }
  return wred(acc);
}

// full-wave softmax over values at idx=lane (v0) and idx=64+lane (v1); -INF = absent
DEV void wsoftmax2(float v0, float v1, float& p0, float& p1){
  float m = fmaxf(v0, v1);
  #pragma unroll
  for (int off=32; off; off>>=1) m = fmaxf(m, __shfl_xor(m, off, 64));
  float e0 = (v0 == -INFINITY) ? 0.f : expf(v0 - m);
  float e1 = (v1 == -INFINITY) ? 0.f : expf(v1 - m);
  float s = e0 + e1;
  #pragma unroll
  for (int off=32; off; off>>=1) s += __shfl_xor(s, off, 64);
  float inv = 1.f / s;
  p0 = e0 * inv; p1 = e1 * inv;
}

// ---------- JAX threefry2x32 (20 rounds) ----------
DEV void threefry(uint k0, uint k1, uint x0, uint x1, uint& o0, uint& o1){
  uint ks2 = k0 ^ k1 ^ 0x1BD11BDAu;
  x0 += k0; x1 += k1;
  #define TFR(r) { x0 += x1; x1 = (x1<<(r))|(x1>>(32-(r))); x1 ^= x0; }
  TFR(13) TFR(15) TFR(26) TFR(6)   x0 += k1;  x1 += ks2 + 1u;
  TFR(17) TFR(29) TFR(16) TFR(24)  x0 += ks2; x1 += k0 + 2u;
  TFR(13) TFR(15) TFR(26) TFR(6)   x0 += k0;  x1 += k1 + 3u;
  TFR(17) TFR(29) TFR(16) TFR(24)  x0 += k1;  x1 += ks2 + 4u;
  TFR(13) TFR(15) TFR(26) TFR(6)   x0 += ks2; x1 += k0 + 5u;
  #undef TFR
  o0 = x0; o1 = x1;
}

DEV void jax_subkey(int i, uint& k0, uint& k1){
#if JAX_PARTITIONABLE
  threefry(0u, 42u, 0u, (uint)i, k0, k1);
#else
  uint L[4], H[4];
  #pragma unroll
  for (int p=0;p<4;p++) threefry(0u,42u,(uint)p,(uint)(4+p),L[p],H[p]);
  uint kk[4][2] = {{L[0],L[1]},{L[2],L[3]},{H[0],H[1]},{H[2],H[3]}};
  k0 = kk[i][0]; k1 = kk[i][1];
#endif
}

DEV uint jax_bits(uint k0, uint k1, int idx, int n){
#if JAX_PARTITIONABLE
  uint o0,o1; threefry(k0,k1,0u,(uint)idx,o0,o1);
  return o0 ^ o1;
#else
  int m = (n+1)/2;
  int p = (idx < m) ? idx : idx - m;
  uint c1 = (p + m <= n-1) ? (uint)(p + m) : 0u;
  uint o0,o1; threefry(k0,k1,(uint)p,c1,o0,o1);
  return (idx < m) ? o0 : o1;
#endif
}

DEV float jax_gumbel(uint k0, uint k1, int idx, int n){
  uint bits = jax_bits(k0,k1,idx,n);
  float f = __uint_as_float((bits >> 9) | 0x3f800000u) - 1.0f;   // [0,1)
  float u = fmaxf(1e-10f, f + 1e-10f);
  return -logf(-logf(u));
}

// ================= K1: colsum partials + independent gemvs =================
__global__ __launch_bounds__(256) void k1(Args A){
  __shared__ float sm[2048];
  const int t = threadIdx.x, b = blockIdx.x;
  const int wv = t >> 6, lane = t & 63;
  const float pa = A.prelu[0];

  if (b < G){                                   // ---- h column-sum partials
    const int cg = t & 127, rl = t >> 7;
    long r0 = (long)b * RPB;
    long r1 = r0 + RPB; if (r1 > NN) r1 = NN;
    float ax=0.f, ay=0.f, az=0.f, aw=0.f;
    for (long r = r0 + rl; r < r1; r += 2){
      float4 v = *(const float4*)(A.h + (size_t)r*512 + cg*4);
      ax += v.x; ay += v.y; az += v.z; aw += v.w;
    }
    sm[rl*512 + cg*4 + 0] = ax;
    sm[rl*512 + cg*4 + 1] = ay;
    sm[rl*512 + cg*4 + 2] = az;
    sm[rl*512 + cg*4 + 3] = aw;
    __syncthreads();
    for (int c = t; c < 512; c += 256)
      A.ws[PART + b*512 + c] = sm[c] + sm[512+c];
  } else if (b < G + 128){                      // ---- goal_embed
    int row = (b - G)*4 + wv;
    float d = wdotf4(A.W_sbert + row*384, A.goalVec, 96, lane) + A.b_sbert[row];
    if (lane==0) A.ws[XCAT + 1536 + row] = preluf(d, pa);
  } else if (b < G + 128 + 1024){               // ---- go[g][j]
    int idx = (b - G - 128)*4 + wv;
    int g = idx >> 9, j = idx & 511;
    float d = wdotf4(A.W_cn + j*300, A.gObj + g*300, 75, lane) + A.b_cn[j];
    if (lane==0) A.ws[GOWS + idx] = preluf(d, pa);
  } else if (b < G + 128 + 1024 + 128){         // ---- predicate LSTM cell
    float* xp = sm;          // 1222
    float* hp = sm + 1222;   // 512
    for (int i=t;i<611;i+=256) xp[i]       = A.pe[i];
    for (int i=t;i<611;i+=256) xp[611+i]   = A.pie[i];
    for (int i=t;i<512;i+=256) hp[i]       = A.hp0[i];
    __syncthreads();
    int j = (b - (G+128+1024))*4 + wv;
    float z[4];
    #pragma unroll
    for (int q=0;q<4;q++){
      int row = j + q*512;
      float d = wdotf2(A.pWih + (size_t)row*1222, xp, 611, lane);
      d += wdotf4(A.pWhh + (size_t)row*512, hp, 128, lane);
      z[q] = d + A.pbih[row] + A.pbhh[row];
    }
    if (lane==0){
      float cc = sigm(z[1])*A.cp0[j] + sigm(z[0])*tanhf(z[2]);
      float hh = sigm(z[3])*tanhf(cc);
      A.ws[XCAT + 2048 + j] = hh;
      A.out[O_PH + j]  = hh;
      A.out[O_CP1 + j] = cc;
    }
  } else {                                      // ---- whh0
    int k = (b - (G+128+1024+128))*4 + wv;
    float d = wdotf4(A.lWhh + (size_t)k*512, A.h0, 128, lane)
            + A.lbih[k] + A.lbhh[k];
    if (lane==0) A.ws[WHH0 + k] = d;
  }
}

// ================= K2: reduce partials + W_gembed gemv -> h_embed ==========
__global__ __launch_bounds__(256) void k2(Args A){
  __shared__ float red[2][512];
  __shared__ float xcs[512];
  const int t = threadIdx.x;
  const int chunk = t & 127, half = t >> 7;
  float4 a = make_float4(0.f,0.f,0.f,0.f);
  const float4* p4 = (const float4*)(A.ws + PART);
  #pragma unroll 8
  for (int g = half*128; g < half*128 + 128; ++g){
    float4 v = p4[g*128 + chunk];
    a.x += v.x; a.y += v.y; a.z += v.z; a.w += v.w;
  }
  *(float4*)&red[half][chunk*4] = a;
  __syncthreads();
  if (t < 128){
    float4 u = *(float4*)&red[0][t*4];
    float4 v = *(float4*)&red[1][t*4];
    float4 s = make_float4(u.x+v.x, u.y+v.y, u.z+v.z, u.w+v.w);
    *(float4*)&xcs[t*4] = s;
  }
  __syncthreads();
  const int wv = t >> 6, lane = t & 63;
  const float pa = A.prelu[0];
  #pragma unroll
  for (int r = 0; r < 2; ++r){
    int row = blockIdx.x*8 + wv + r*4;
    float d = wdotf4(A.W_gembed + (size_t)row*512, xcs, 128, lane) + A.b_gembed[row];
    if (lane==0) A.ws[XCAT + row] = preluf(d, pa);
  }
}

// ================= K3: graph LSTM + goal-object attention ==================
__global__ __launch_bounds__(256) void k3(Args A){
  __shared__ float sm[4624];
  const int t = threadIdx.x, b = blockIdx.x;
  const int wv = t >> 6, lane = t & 63;
  float* sh = sm;
  for (int i=t;i<512;i+=256) sh[i] = A.ws[XCAT + i];
  if (b < 128){
    __syncthreads();
    int j = b*4 + wv;
    float zi = wdotf4(A.lWih + (size_t)(j       )*512, sh, 128, lane) + A.ws[WHH0 + j];
    float zf = wdotf4(A.lWih + (size_t)(j +  512)*512, sh, 128, lane) + A.ws[WHH0 + j + 512];
    float zg = wdotf4(A.lWih + (size_t)(j + 1024)*512, sh, 128, lane) + A.ws[WHH0 + j + 1024];
    float zo = wdotf4(A.lWih + (size_t)(j + 1536)*512, sh, 128, lane) + A.ws[WHH0 + j + 1536];
    if (lane==0){
      float cc = sigm(zf)*A.c0[j] + sigm(zi)*tanhf(zg);
      float hh = sigm(zo)*tanhf(cc);
      A.ws[XCAT + 512 + j] = hh;
      A.out[O_HH + j] = hh;
      A.out[O_C1 + j] = cc;
    }
  } else {
    float* sgo = sm + 512; float* tl = sm + 4608; float* aw = sm + 4616;
    for (int i=t;i<4096;i+=256) sgo[i] = A.ws[GOWS + i];
    __syncthreads();
    float common = wdotf4(A.W_goattn, sh, 128, lane);
    for (int g = wv; g < 8; g += 4){
      float t2 = wdotf4(A.W_goattn + 512, sgo + g*512, 128, lane);
      if (lane==0) tl[g] = common + t2 + A.b_goattn[0];
    }
    __syncthreads();
    if (wv == 0){
      float v0 = lane < 8 ? tl[lane] : -INFINITY;
      float p0, p1; wsoftmax2(v0, -INFINITY, p0, p1);
      if (lane < 8) aw[lane] = p0;
    }
    __syncthreads();
    for (int j = t; j < 512; j += 256){
      float s = 0.f;
      #pragma unroll
      for (int g=0; g<8; g++) s += aw[g]*sgo[g*512 + j];
      A.ws[XCAT + 1024 + j] = s;
    }
  }
}

// ================= K4: final = prelu(W_fc @ xcat + b_fc) ===================
__global__ __launch_bounds__(256) void k4(Args A){
  __shared__ float xc[2560];
  const int t = threadIdx.x;
  for (int i=t;i<2560;i+=256) xc[i] = A.ws[XCAT + i];
  __syncthreads();
  const int wv = t >> 6, lane = t & 63;
  const float pa = A.prelu[0];
  int row = blockIdx.x*4 + wv;
  float d = wdotf4(A.W_fc + (size_t)row*2560, xc, 640, lane) + A.b_fc[row];
  if (lane==0) A.ws[FINALW + row] = preluf(d, pa);
}

// ============ K4b: base gemvs over final (col 0..511 slices) ==============
// rows: [0,128) obj1-fwd | [128,256) obj1-inv | [256,384) obj2 |
//       [384,400) state  | [400,411) act-fwd  | [411,422) act-inv
__global__ __launch_bounds__(256) void k4b(Args A){
  __shared__ float sfin[512];
  const int t = threadIdx.x, wv = t >> 6, lane = t & 63;
  for (int i=t;i<512;i+=256) sfin[i] = A.ws[FINALW + i];
  __syncthreads();
  int r = blockIdx.x*4 + wv;
  if (r >= 422) return;
  const float* w; float bias; int dst;
  if (r < 128)      { w = A.W_obj1  + (size_t)r*523;        bias = A.b_obj1[r];       dst = B1F + r; }
  else if (r < 256) { int q=r-128; w = A.W_obj1i + (size_t)q*523; bias = A.b_obj1i[q]; dst = B1F + r; }
  else if (r < 384) { int q=r-256; w = A.W_obj2  + (size_t)q*651; bias = A.b_obj2[q];  dst = B2F + q; }
  else if (r < 400) { int q=r-384; w = A.W_state + (size_t)q*651; bias = A.b_state[q]; dst = BSF + q; }
  else if (r < 411) { int q=r-400; w = A.W_act   + (size_t)q*512; bias = A.b_act[q];   dst = LAW + q; }
  else              { int q=r-411; w = A.W_acti  + (size_t)q*512; bias = A.b_acti[q];  dst = LAW + 11 + q; }
  float acc = 0.f;
  #pragma unroll
  for (int i = 0; i < 8; ++i)
    acc += w[lane + i*64] * sfin[lane + i*64];
  acc = wred(acc) + bias;
  if (lane==0) A.ws[dst] = acc;
}

// ================= K5: decode chains (block 0 = fwd, block 1 = inv) ========
__global__ __launch_bounds__(256) void k5(Args A){
  __shared__ float xcorr[139];   // [0,11): oh_a  [11,139): oh_p1
  __shared__ float lg[144];      // p1 logits then p2/s2 logits
  __shared__ uint kk[2][2];
  const int t = threadIdx.x, wv = t >> 6, lane = t & 63;
  const int chain = blockIdx.x;
  if (t < 2){ uint a,b2; jax_subkey(chain*2 + t, a, b2); kk[t][0]=a; kk[t][1]=b2; }
  __syncthreads();
  // phase 1: action softmax + gumbel -> oh_a
  if (wv == 0){
    float v0 = lane < 11 ? A.ws[LAW + chain*11 + lane] : -INFINITY;
    float p0, pd; wsoftmax2(v0, -INFINITY, p0, pd);
    if (lane < 11) A.out[(chain ? O_ACTI : O_ACT) + lane] = p0;
    float gl = lane < 11 ? (p0 + jax_gumbel(kk[0][0],kk[0][1],lane,11)) / 0.01f : -INFINITY;
    float o0, o1; wsoftmax2(gl, -INFINITY, o0, o1);
    if (lane < 11) xcorr[lane] = o0;
  }
  __syncthreads();
  // phase 2: p1 logits = base + W[:,512:523] @ oh_a  (thread-per-row)
  if (t < 128){
    const float* W1 = chain ? A.W_obj1i : A.W_obj1;
    const float* wr = W1 + (size_t)t*523 + 512;
    float acc = A.ws[B1F + chain*128 + t];
    #pragma unroll
    for (int j = 0; j < 11; ++j) acc += wr[j] * xcorr[j];
    lg[t] = acc;
  }
  __syncthreads();
  // phase 3: p1 softmax + gumbel -> oh_p1
  if (wv == 0){
    float p0, p1; wsoftmax2(lg[lane], lg[64+lane], p0, p1);
    int base = chain ? O_P1I : O_P1;
    A.out[base + lane] = p0; A.out[base + 64 + lane] = p1;
    float g0 = (p0 + jax_gumbel(kk[1][0],kk[1][1],lane,128))    / 0.01f;
    float g1 = (p1 + jax_gumbel(kk[1][0],kk[1][1],lane+64,128)) / 0.01f;
    float o0, o1; wsoftmax2(g0, g1, o0, o1);
    xcorr[11 + lane] = o0; xcorr[11 + 64 + lane] = o1;
  }
  __syncthreads();
  // phase 4: p2/s2 logits = base + W[:,512:651] @ [oh_a|oh_p1] (thread-per-row)
  if (t < 144){
    const float* wr; float acc;
    if (t < 128){ wr = A.W_obj2  + (size_t)t*651 + 512;       acc = A.ws[B2F + t]; }
    else        { wr = A.W_state + (size_t)(t-128)*651 + 512; acc = A.ws[BSF + t - 128]; }
    #pragma unroll 16
    for (int j = 0; j < 139; ++j) acc += wr[j] * xcorr[j];
    lg[t] = acc;
  }
  __syncthreads();
  // phase 5: softmaxes
  if (wv == 0){
    float p0, p1; wsoftmax2(lg[lane], lg[64+lane], p0, p1);
    int base = chain ? O_P2I : O_P2;
    A.out[base + lane] = p0; A.out[base + 64 + lane] = p1;
  } else if (wv == 1){
    float v0 = lane < 16 ? lg[128 + lane] : -INFINITY;
    float p0, p1; wsoftmax2(v0, -INFINITY, p0, p1);
    int base = chain ? O_S2I : O_S2;
    if (lane < 16) A.out[base + lane] = p0;
  }
}

// ================= host =================
extern "C" void kernel_launch(void* const* d_in, const int* in_sizes, int n_in,
                              void* d_out, int out_size, void* d_ws, size_t ws_size,
                              hipStream_t stream){
  Args A;
  A.h       = (const float*)d_in[0];
  A.goalVec = (const float*)d_in[1];
  A.gObj    = (const float*)d_in[2];
  A.pe      = (const float*)d_in[3];
  A.pie     = (const float*)d_in[4];
  A.h0      = (const float*)d_in[5];
  A.c0      = (const float*)d_in[6];
  A.hp0     = (const float*)d_in[7];
  A.cp0     = (const float*)d_in[8];
  A.prelu   = (const float*)d_in[9];
  A.W_sbert = (const float*)d_in[10]; A.b_sbert = (const float*)d_in[11];
  A.W_cn    = (const float*)d_in[12]; A.b_cn    = (const float*)d_in[13];
  // d_in[14], d_in[15] (W_gattn, b_gattn) dead: softmax over axis of size 1 == 1.0
  A.W_gembed= (const float*)d_in[16]; A.b_gembed= (const float*)d_in[17];
  A.W_goattn= (const float*)d_in[18]; A.b_goattn= (const float*)d_in[19];
  A.W_fc    = (const float*)d_in[20]; A.b_fc    = (const float*)d_in[21];
  A.lWih    = (const float*)d_in[22]; A.lWhh    = (const float*)d_in[23];
  A.lbih    = (const float*)d_in[24]; A.lbhh    = (const float*)d_in[25];
  A.pWih    = (const float*)d_in[26]; A.pWhh    = (const float*)d_in[27];
  A.pbih    = (const float*)d_in[28]; A.pbhh    = (const float*)d_in[29];
  A.W_act   = (const float*)d_in[30]; A.b_act   = (const float*)d_in[31];
  A.W_obj1  = (const float*)d_in[32]; A.b_obj1  = (const float*)d_in[33];
  A.W_obj2  = (const float*)d_in[34]; A.b_obj2  = (const float*)d_in[35];
  A.W_state = (const float*)d_in[36]; A.b_state = (const float*)d_in[37];
  A.W_acti  = (const float*)d_in[38]; A.b_acti  = (const float*)d_in[39];
  A.W_obj1i = (const float*)d_in[40]; A.b_obj1i = (const float*)d_in[41];
  A.out = (float*)d_out;
  A.ws  = (float*)d_ws;

  k1 <<<G + 128 + 1024 + 128 + 512, 256, 0, stream>>>(A);
  k2 <<<64,  256, 0, stream>>>(A);
  k3 <<<129, 256, 0, stream>>>(A);
  k4 <<<128, 256, 0, stream>>>(A);
  k4b<<<106, 256, 0, stream>>>(A);
  k5 <<<2,   256, 0, stream>>>(A);
}

// Round 4
// 423.079 us; speedup vs baseline: 2.2999x; 1.1222x over previous
//
#include <hip/hip_runtime.h>

typedef unsigned int uint;

#define DEV __device__ __forceinline__

#define JAX_PARTITIONABLE 1   // confirmed correct by round-2 pass

// ---------- problem constants ----------
constexpr int NN  = 100000;   // nodes
constexpr int G   = 256;      // colsum partial blocks
constexpr int RPB = 391;      // rows per colsum block (G*RPB = 100096 >= NN)

// ws layout (float offsets)
constexpr int XCAT  = 0;      // 2560: [h_embed | h_hist | goal_obj | goal_embed | pred_hist]
constexpr int GOWS  = 2560;   // 4096: go (8 x 512)
constexpr int WHH0  = 6656;   // 2048: lstm_Whh@h0 + bih + bhh
constexpr int FINALW= 8704;   // 512
constexpr int B1F   = 9216;   // 256: obj1 base (fwd 128, inv 128)
constexpr int B2F   = 9472;   // 128: obj2 base (shared by fwd/inv)
constexpr int BSF   = 9600;   // 16:  state base (shared)
constexpr int LAW   = 9616;   // 22:  action logits (fwd 11, inv 11)
constexpr int PART  = 9728;   // G*512 colsum partials

// out offsets (elements)
constexpr int O_ACT=0, O_P1=11, O_P2=139, O_S2=267, O_ACTI=283, O_P1I=294,
              O_P2I=422, O_S2I=550, O_HH=566, O_C1=1078, O_PH=1590, O_CP1=2102;

struct Args {
  const float *h, *goalVec, *gObj, *pe, *pie, *h0, *c0, *hp0, *cp0, *prelu;
  const float *W_sbert,*b_sbert,*W_cn,*b_cn,*W_gembed,*b_gembed,*W_goattn,*b_goattn,*W_fc,*b_fc;
  const float *lWih,*lWhh,*lbih,*lbhh,*pWih,*pWhh,*pbih,*pbhh;
  const float *W_act,*b_act,*W_obj1,*b_obj1,*W_obj2,*b_obj2,*W_state,*b_state;
  const float *W_acti,*b_acti,*W_obj1i,*b_obj1i;
  float* out;
  float* ws;
};

// ---------- small utils ----------
DEV float sigm(float x){ return 1.f/(1.f+expf(-x)); }
DEV float preluf(float x, float a){ return x >= 0.f ? x : a*x; }

DEV float wred(float v){
  #pragma unroll
  for (int off=32; off; off>>=1) v += __shfl_xor(v, off, 64);
  return v;
}

DEV float wdotf4(const float* w, const float* x, int n4, int lane){ // both 16B-aligned
  float acc = 0.f;
  for (int c = lane; c < n4; c += 64){
    float4 a = ((const float4*)w)[c];
    float4 b = ((const float4*)x)[c];
    acc += a.x*b.x + a.y*b.y + a.z*b.z + a.w*b.w;
  }
  return wred(acc);
}
DEV float wdotf2(const float* w, const float* x, int n2, int lane){ // 8B-aligned w
  float acc = 0.f;
  #pragma unroll 4
  for (int c = lane; c < n2; c += 64){
    float2 a = ((const float2*)w)[c];
    acc += a.x*x[2*c] + a.y*x[2*c+1];
  }
  return wred(acc);
}

// full-wave softmax over values at idx=lane (v0) and idx=64+lane (v1); -INF = absent
DEV void wsoftmax2(float v0, float v1, float& p0, float& p1){
  float m = fmaxf(v0, v1);
  #pragma unroll
  for (int off=32; off; off>>=1) m = fmaxf(m, __shfl_xor(m, off, 64));
  float e0 = (v0 == -INFINITY) ? 0.f : expf(v0 - m);
  float e1 = (v1 == -INFINITY) ? 0.f : expf(v1 - m);
  float s = e0 + e1;
  #pragma unroll
  for (int off=32; off; off>>=1) s += __shfl_xor(s, off, 64);
  float inv = 1.f / s;
  p0 = e0 * inv; p1 = e1 * inv;
}

// ---------- JAX threefry2x32 (20 rounds) ----------
DEV void threefry(uint k0, uint k1, uint x0, uint x1, uint& o0, uint& o1){
  uint ks2 = k0 ^ k1 ^ 0x1BD11BDAu;
  x0 += k0; x1 += k1;
  #define TFR(r) { x0 += x1; x1 = (x1<<(r))|(x1>>(32-(r))); x1 ^= x0; }
  TFR(13) TFR(15) TFR(26) TFR(6)   x0 += k1;  x1 += ks2 + 1u;
  TFR(17) TFR(29) TFR(16) TFR(24)  x0 += ks2; x1 += k0 + 2u;
  TFR(13) TFR(15) TFR(26) TFR(6)   x0 += k0;  x1 += k1 + 3u;
  TFR(17) TFR(29) TFR(16) TFR(24)  x0 += k1;  x1 += ks2 + 4u;
  TFR(13) TFR(15) TFR(26) TFR(6)   x0 += ks2; x1 += k0 + 5u;
  #undef TFR
  o0 = x0; o1 = x1;
}

DEV void jax_subkey(int i, uint& k0, uint& k1){
#if JAX_PARTITIONABLE
  threefry(0u, 42u, 0u, (uint)i, k0, k1);
#else
  uint L[4], H[4];
  #pragma unroll
  for (int p=0;p<4;p++) threefry(0u,42u,(uint)p,(uint)(4+p),L[p],H[p]);
  uint kk[4][2] = {{L[0],L[1]},{L[2],L[3]},{H[0],H[1]},{H[2],H[3]}};
  k0 = kk[i][0]; k1 = kk[i][1];
#endif
}

DEV uint jax_bits(uint k0, uint k1, int idx, int n){
#if JAX_PARTITIONABLE
  uint o0,o1; threefry(k0,k1,0u,(uint)idx,o0,o1);
  return o0 ^ o1;
#else
  int m = (n+1)/2;
  int p = (idx < m) ? idx : idx - m;
  uint c1 = (p + m <= n-1) ? (uint)(p + m) : 0u;
  uint o0,o1; threefry(k0,k1,(uint)p,c1,o0,o1);
  return (idx < m) ? o0 : o1;
#endif
}

DEV float jax_gumbel(uint k0, uint k1, int idx, int n){
  uint bits = jax_bits(k0,k1,idx,n);
  float f = __uint_as_float((bits >> 9) | 0x3f800000u) - 1.0f;   // [0,1)
  float u = fmaxf(1e-10f, f + 1e-10f);
  return -logf(-logf(u));
}

// ================= K1: colsum partials + independent gemvs =================
__global__ __launch_bounds__(256) void k1(Args A){
  __shared__ float sm[2048];
  const int t = threadIdx.x, b = blockIdx.x;
  const int wv = t >> 6, lane = t & 63;
  const float pa = A.prelu[0];

  if (b < G){                                   // ---- h column-sum partials
    // 128 col-threads x 4 floats = 512 cols; 2 row-lanes; 8-way row unroll
    // so 8 independent 16B loads are in flight per thread (latency-bound fix,
    // round-3 post-mortem: 1 load in flight -> 831 GB/s).
    const int cg = t & 127, rl = t >> 7;
    long r0 = (long)b * RPB;
    long r1 = r0 + RPB; if (r1 > NN) r1 = NN;
    const float* base = A.h + (size_t)cg*4;
    float ax=0.f, ay=0.f, az=0.f, aw=0.f;
    long r = r0 + rl;
    for (; r + 14 < r1; r += 16){
      float4 v0 = *(const float4*)(base + (size_t)(r     )*512);
      float4 v1 = *(const float4*)(base + (size_t)(r +  2)*512);
      float4 v2 = *(const float4*)(base + (size_t)(r +  4)*512);
      float4 v3 = *(const float4*)(base + (size_t)(r +  6)*512);
      float4 v4 = *(const float4*)(base + (size_t)(r +  8)*512);
      float4 v5 = *(const float4*)(base + (size_t)(r + 10)*512);
      float4 v6 = *(const float4*)(base + (size_t)(r + 12)*512);
      float4 v7 = *(const float4*)(base + (size_t)(r + 14)*512);
      ax += v0.x+v1.x+v2.x+v3.x + v4.x+v5.x+v6.x+v7.x;
      ay += v0.y+v1.y+v2.y+v3.y + v4.y+v5.y+v6.y+v7.y;
      az += v0.z+v1.z+v2.z+v3.z + v4.z+v5.z+v6.z+v7.z;
      aw += v0.w+v1.w+v2.w+v3.w + v4.w+v5.w+v6.w+v7.w;
    }
    for (; r < r1; r += 2){
      float4 v = *(const float4*)(base + (size_t)r*512);
      ax += v.x; ay += v.y; az += v.z; aw += v.w;
    }
    sm[rl*512 + cg*4 + 0] = ax;
    sm[rl*512 + cg*4 + 1] = ay;
    sm[rl*512 + cg*4 + 2] = az;
    sm[rl*512 + cg*4 + 3] = aw;
    __syncthreads();
    for (int c = t; c < 512; c += 256)
      A.ws[PART + b*512 + c] = sm[c] + sm[512+c];
  } else if (b < G + 128){                      // ---- goal_embed
    int row = (b - G)*4 + wv;
    float d = wdotf4(A.W_sbert + row*384, A.goalVec, 96, lane) + A.b_sbert[row];
    if (lane==0) A.ws[XCAT + 1536 + row] = preluf(d, pa);
  } else if (b < G + 128 + 1024){               // ---- go[g][j]
    int idx = (b - G - 128)*4 + wv;
    int g = idx >> 9, j = idx & 511;
    float d = wdotf4(A.W_cn + j*300, A.gObj + g*300, 75, lane) + A.b_cn[j];
    if (lane==0) A.ws[GOWS + idx] = preluf(d, pa);
  } else if (b < G + 128 + 1024 + 128){         // ---- predicate LSTM cell
    float* xp = sm;          // 1222
    float* hp = sm + 1222;   // 512
    for (int i=t;i<611;i+=256) xp[i]       = A.pe[i];
    for (int i=t;i<611;i+=256) xp[611+i]   = A.pie[i];
    for (int i=t;i<512;i+=256) hp[i]       = A.hp0[i];
    __syncthreads();
    int j = (b - (G+128+1024))*4 + wv;
    float z[4];
    #pragma unroll
    for (int q=0;q<4;q++){
      int row = j + q*512;
      float d = wdotf2(A.pWih + (size_t)row*1222, xp, 611, lane);
      d += wdotf4(A.pWhh + (size_t)row*512, hp, 128, lane);
      z[q] = d + A.pbih[row] + A.pbhh[row];
    }
    if (lane==0){
      float cc = sigm(z[1])*A.cp0[j] + sigm(z[0])*tanhf(z[2]);
      float hh = sigm(z[3])*tanhf(cc);
      A.ws[XCAT + 2048 + j] = hh;
      A.out[O_PH + j]  = hh;
      A.out[O_CP1 + j] = cc;
    }
  } else {                                      // ---- whh0
    int k = (b - (G+128+1024+128))*4 + wv;
    float d = wdotf4(A.lWhh + (size_t)k*512, A.h0, 128, lane)
            + A.lbih[k] + A.lbhh[k];
    if (lane==0) A.ws[WHH0 + k] = d;
  }
}

// ================= K2: reduce partials + W_gembed gemv -> h_embed ==========
__global__ __launch_bounds__(256) void k2(Args A){
  __shared__ float red[2][512];
  __shared__ float xcs[512];
  const int t = threadIdx.x;
  const int chunk = t & 127, half = t >> 7;
  float4 a = make_float4(0.f,0.f,0.f,0.f);
  const float4* p4 = (const float4*)(A.ws + PART);
  #pragma unroll 8
  for (int g = half*128; g < half*128 + 128; ++g){
    float4 v = p4[g*128 + chunk];
    a.x += v.x; a.y += v.y; a.z += v.z; a.w += v.w;
  }
  *(float4*)&red[half][chunk*4] = a;
  __syncthreads();
  if (t < 128){
    float4 u = *(float4*)&red[0][t*4];
    float4 v = *(float4*)&red[1][t*4];
    float4 s = make_float4(u.x+v.x, u.y+v.y, u.z+v.z, u.w+v.w);
    *(float4*)&xcs[t*4] = s;
  }
  __syncthreads();
  const int wv = t >> 6, lane = t & 63;
  const float pa = A.prelu[0];
  #pragma unroll
  for (int r = 0; r < 2; ++r){
    int row = blockIdx.x*8 + wv + r*4;
    float d = wdotf4(A.W_gembed + (size_t)row*512, xcs, 128, lane) + A.b_gembed[row];
    if (lane==0) A.ws[XCAT + row] = preluf(d, pa);
  }
}

// ================= K3: graph LSTM + goal-object attention ==================
__global__ __launch_bounds__(256) void k3(Args A){
  __shared__ float sm[4624];
  const int t = threadIdx.x, b = blockIdx.x;
  const int wv = t >> 6, lane = t & 63;
  float* sh = sm;
  for (int i=t;i<512;i+=256) sh[i] = A.ws[XCAT + i];
  if (b < 128){
    __syncthreads();
    int j = b*4 + wv;
    float zi = wdotf4(A.lWih + (size_t)(j       )*512, sh, 128, lane) + A.ws[WHH0 + j];
    float zf = wdotf4(A.lWih + (size_t)(j +  512)*512, sh, 128, lane) + A.ws[WHH0 + j + 512];
    float zg = wdotf4(A.lWih + (size_t)(j + 1024)*512, sh, 128, lane) + A.ws[WHH0 + j + 1024];
    float zo = wdotf4(A.lWih + (size_t)(j + 1536)*512, sh, 128, lane) + A.ws[WHH0 + j + 1536];
    if (lane==0){
      float cc = sigm(zf)*A.c0[j] + sigm(zi)*tanhf(zg);
      float hh = sigm(zo)*tanhf(cc);
      A.ws[XCAT + 512 + j] = hh;
      A.out[O_HH + j] = hh;
      A.out[O_C1 + j] = cc;
    }
  } else {
    float* sgo = sm + 512; float* tl = sm + 4608; float* aw = sm + 4616;
    for (int i=t;i<4096;i+=256) sgo[i] = A.ws[GOWS + i];
    __syncthreads();
    float common = wdotf4(A.W_goattn, sh, 128, lane);
    for (int g = wv; g < 8; g += 4){
      float t2 = wdotf4(A.W_goattn + 512, sgo + g*512, 128, lane);
      if (lane==0) tl[g] = common + t2 + A.b_goattn[0];
    }
    __syncthreads();
    if (wv == 0){
      float v0 = lane < 8 ? tl[lane] : -INFINITY;
      float p0, p1; wsoftmax2(v0, -INFINITY, p0, p1);
      if (lane < 8) aw[lane] = p0;
    }
    __syncthreads();
    for (int j = t; j < 512; j += 256){
      float s = 0.f;
      #pragma unroll
      for (int g=0; g<8; g++) s += aw[g]*sgo[g*512 + j];
      A.ws[XCAT + 1024 + j] = s;
    }
  }
}

// ================= K4: final = prelu(W_fc @ xcat + b_fc) ===================
__global__ __launch_bounds__(256) void k4(Args A){
  __shared__ float xc[2560];
  const int t = threadIdx.x;
  for (int i=t;i<2560;i+=256) xc[i] = A.ws[XCAT + i];
  __syncthreads();
  const int wv = t >> 6, lane = t & 63;
  const float pa = A.prelu[0];
  int row = blockIdx.x*4 + wv;
  // fully-unrolled: 10 independent float4 loads in flight per lane
  const float4* wr = (const float4*)(A.W_fc + (size_t)row*2560);
  const float4* xr = (const float4*)xc;
  float acc = 0.f;
  #pragma unroll
  for (int i = 0; i < 10; ++i){
    float4 a = wr[lane + i*64];
    float4 b = xr[lane + i*64];
    acc += a.x*b.x + a.y*b.y + a.z*b.z + a.w*b.w;
  }
  float d = wred(acc) + A.b_fc[row];
  if (lane==0) A.ws[FINALW + row] = preluf(d, pa);
}

// ============ K4b: base gemvs over final (col 0..511 slices) ==============
// rows: [0,128) obj1-fwd | [128,256) obj1-inv | [256,384) obj2 |
//       [384,400) state  | [400,411) act-fwd  | [411,422) act-inv
__global__ __launch_bounds__(256) void k4b(Args A){
  __shared__ float sfin[512];
  const int t = threadIdx.x, wv = t >> 6, lane = t & 63;
  for (int i=t;i<512;i+=256) sfin[i] = A.ws[FINALW + i];
  __syncthreads();
  int r = blockIdx.x*4 + wv;
  if (r >= 422) return;
  const float* w; float bias; int dst;
  if (r < 128)      { w = A.W_obj1  + (size_t)r*523;        bias = A.b_obj1[r];       dst = B1F + r; }
  else if (r < 256) { int q=r-128; w = A.W_obj1i + (size_t)q*523; bias = A.b_obj1i[q]; dst = B1F + r; }
  else if (r < 384) { int q=r-256; w = A.W_obj2  + (size_t)q*651; bias = A.b_obj2[q];  dst = B2F + q; }
  else if (r < 400) { int q=r-384; w = A.W_state + (size_t)q*651; bias = A.b_state[q]; dst = BSF + q; }
  else if (r < 411) { int q=r-400; w = A.W_act   + (size_t)q*512; bias = A.b_act[q];   dst = LAW + q; }
  else              { int q=r-411; w = A.W_acti  + (size_t)q*512; bias = A.b_acti[q];  dst = LAW + 11 + q; }
  float acc = 0.f;
  #pragma unroll
  for (int i = 0; i < 8; ++i)
    acc += w[lane + i*64] * sfin[lane + i*64];
  acc = wred(acc) + bias;
  if (lane==0) A.ws[dst] = acc;
}

// ================= K5: decode chains (block 0 = fwd, block 1 = inv) ========
__global__ __launch_bounds__(256) void k5(Args A){
  __shared__ float xcorr[139];   // [0,11): oh_a  [11,139): oh_p1
  __shared__ float lg[144];      // p1 logits then p2/s2 logits
  __shared__ uint kk[2][2];
  const int t = threadIdx.x, wv = t >> 6, lane = t & 63;
  const int chain = blockIdx.x;
  if (t < 2){ uint a,b2; jax_subkey(chain*2 + t, a, b2); kk[t][0]=a; kk[t][1]=b2; }
  __syncthreads();
  // phase 1: action softmax + gumbel -> oh_a
  if (wv == 0){
    float v0 = lane < 11 ? A.ws[LAW + chain*11 + lane] : -INFINITY;
    float p0, pd; wsoftmax2(v0, -INFINITY, p0, pd);
    if (lane < 11) A.out[(chain ? O_ACTI : O_ACT) + lane] = p0;
    float gl = lane < 11 ? (p0 + jax_gumbel(kk[0][0],kk[0][1],lane,11)) / 0.01f : -INFINITY;
    float o0, o1; wsoftmax2(gl, -INFINITY, o0, o1);
    if (lane < 11) xcorr[lane] = o0;
  }
  __syncthreads();
  // phase 2: p1 logits = base + W[:,512:523] @ oh_a  (thread-per-row)
  if (t < 128){
    const float* W1 = chain ? A.W_obj1i : A.W_obj1;
    const float* wr = W1 + (size_t)t*523 + 512;
    float acc = A.ws[B1F + chain*128 + t];
    #pragma unroll
    for (int j = 0; j < 11; ++j) acc += wr[j] * xcorr[j];
    lg[t] = acc;
  }
  __syncthreads();
  // phase 3: p1 softmax + gumbel -> oh_p1
  if (wv == 0){
    float p0, p1; wsoftmax2(lg[lane], lg[64+lane], p0, p1);
    int base = chain ? O_P1I : O_P1;
    A.out[base + lane] = p0; A.out[base + 64 + lane] = p1;
    float g0 = (p0 + jax_gumbel(kk[1][0],kk[1][1],lane,128))    / 0.01f;
    float g1 = (p1 + jax_gumbel(kk[1][0],kk[1][1],lane+64,128)) / 0.01f;
    float o0, o1; wsoftmax2(g0, g1, o0, o1);
    xcorr[11 + lane] = o0; xcorr[11 + 64 + lane] = o1;
  }
  __syncthreads();
  // phase 4: p2/s2 logits = base + W[:,512:651] @ [oh_a|oh_p1] (thread-per-row)
  if (t < 144){
    const float* wr; float acc;
    if (t < 128){ wr = A.W_obj2  + (size_t)t*651 + 512;       acc = A.ws[B2F + t]; }
    else        { wr = A.W_state + (size_t)(t-128)*651 + 512; acc = A.ws[BSF + t - 128]; }
    #pragma unroll 16
    for (int j = 0; j < 139; ++j) acc += wr[j] * xcorr[j];
    lg[t] = acc;
  }
  __syncthreads();
  // phase 5: softmaxes
  if (wv == 0){
    float p0, p1; wsoftmax2(lg[lane], lg[64+lane], p0, p1);
    int base = chain ? O_P2I : O_P2;
    A.out[base + lane] = p0; A.out[base + 64 + lane] = p1;
  } else if (wv == 1){
    float v0 = lane < 16 ? lg[128 + lane] : -INFINITY;
    float p0, p1; wsoftmax2(v0, -INFINITY, p0, p1);
    int base = chain ? O_S2I : O_S2;
    if (lane < 16) A.out[base + lane] = p0;
  }
}

// ================= host =================
extern "C" void kernel_launch(void* const* d_in, const int* in_sizes, int n_in,
                              void* d_out, int out_size, void* d_ws, size_t ws_size,
                              hipStream_t stream){
  Args A;
  A.h       = (const float*)d_in[0];
  A.goalVec = (const float*)d_in[1];
  A.gObj    = (const float*)d_in[2];
  A.pe      = (const float*)d_in[3];
  A.pie     = (const float*)d_in[4];
  A.h0      = (const float*)d_in[5];
  A.c0      = (const float*)d_in[6];
  A.hp0     = (const float*)d_in[7];
  A.cp0     = (const float*)d_in[8];
  A.prelu   = (const float*)d_in[9];
  A.W_sbert = (const float*)d_in[10]; A.b_sbert = (const float*)d_in[11];
  A.W_cn    = (const float*)d_in[12]; A.b_cn    = (const float*)d_in[13];
  // d_in[14], d_in[15] (W_gattn, b_gattn) dead: softmax over axis of size 1 == 1.0
  A.W_gembed= (const float*)d_in[16]; A.b_gembed= (const float*)d_in[17];
  A.W_goattn= (const float*)d_in[18]; A.b_goattn= (const float*)d_in[19];
  A.W_fc    = (const float*)d_in[20]; A.b_fc    = (const float*)d_in[21];
  A.lWih    = (const float*)d_in[22]; A.lWhh    = (const float*)d_in[23];
  A.lbih    = (const float*)d_in[24]; A.lbhh    = (const float*)d_in[25];
  A.pWih    = (const float*)d_in[26]; A.pWhh    = (const float*)d_in[27];
  A.pbih    = (const float*)d_in[28]; A.pbhh    = (const float*)d_in[29];
  A.W_act   = (const float*)d_in[30]; A.b_act   = (const float*)d_in[31];
  A.W_obj1  = (const float*)d_in[32]; A.b_obj1  = (const float*)d_in[33];
  A.W_obj2  = (const float*)d_in[34]; A.b_obj2  = (const float*)d_in[35];
  A.W_state = (const float*)d_in[36]; A.b_state = (const float*)d_in[37];
  A.W_acti  = (const float*)d_in[38]; A.b_acti  = (const float*)d_in[39];
  A.W_obj1i = (const float*)d_in[40]; A.b_obj1i = (const float*)d_in[41];
  A.out = (float*)d_out;
  A.ws  = (float*)d_ws;

  k1 <<<G + 128 + 1024 + 128 + 512, 256, 0, stream>>>(A);
  k2 <<<64,  256, 0, stream>>>(A);
  k3 <<<129, 256, 0, stream>>>(A);
  k4 <<<128, 256, 0, stream>>>(A);
  k4b<<<106, 256, 0, stream>>>(A);
  k5 <<<2,   256, 0, stream>>>(A);
}